// Round 1
// baseline (23.237 us; speedup 1.0000x reference)
//
#include <hip/hip_runtime.h>
#include <hip/hip_bf16.h>

// Problem constants (SparseEmbeddingHead): B=32, S=512, H=1024, V=250002
#define BB 32
#define SS 512
#define HH 1024
#define VV 250002

// One wave (64 lanes) per token. Each lane reads 4x float4 (H=1024 floats /
// 64 lanes = 16 floats = 4 float4). W is 4KB and stays L1/L2-resident.
__global__ __launch_bounds__(256) void sparse_head_kernel(
    const float* __restrict__ hidden,   // [B*S, H]
    const int* __restrict__ ids,        // [B*S]
    const float* __restrict__ mask,     // [B*S]
    const float* __restrict__ W,        // [H]
    const float* __restrict__ bias,     // [1]
    float* __restrict__ out)            // [B, V] (pre-zeroed)
{
    const int wave_in_block = threadIdx.x >> 6;
    const int lane = threadIdx.x & 63;
    const int token = blockIdx.x * (blockDim.x >> 6) + wave_in_block;
    if (token >= BB * SS) return;

    const float4* __restrict__ h4 = reinterpret_cast<const float4*>(hidden + (size_t)token * HH);
    const float4* __restrict__ w4 = reinterpret_cast<const float4*>(W);

    float sum = 0.0f;
#pragma unroll
    for (int i = 0; i < 4; ++i) {
        const float4 hv = h4[i * 64 + lane];
        const float4 wv = w4[i * 64 + lane];
        sum = fmaf(hv.x, wv.x, sum);
        sum = fmaf(hv.y, wv.y, sum);
        sum = fmaf(hv.z, wv.z, sum);
        sum = fmaf(hv.w, wv.w, sum);
    }

    // 64-lane butterfly reduction
#pragma unroll
    for (int off = 32; off > 0; off >>= 1)
        sum += __shfl_xor(sum, off, 64);

    if (lane == 0) {
        float tw = (sum + bias[0]) * mask[token];
        tw = fmaxf(tw, 0.0f);
        if (tw != 0.0f) {
            const int b = token / SS;
            const int id = ids[token];
            atomicAdd(&out[(size_t)b * VV + id], tw);
        }
    }
}

extern "C" void kernel_launch(void* const* d_in, const int* in_sizes, int n_in,
                              void* d_out, int out_size, void* d_ws, size_t ws_size,
                              hipStream_t stream) {
    const float* hidden = (const float*)d_in[0];
    const int*   ids    = (const int*)d_in[1];
    const float* mask   = (const float*)d_in[2];
    const float* W      = (const float*)d_in[3];
    const float* bias   = (const float*)d_in[4];
    float* out = (float*)d_out;

    // Zero the (B,V) output accumulator (async, graph-capturable).
    hipMemsetAsync(out, 0, (size_t)out_size * sizeof(float), stream);

    const int tokens = BB * SS;               // 16384
    const int waves_per_block = 4;            // 256 threads
    const int blocks = tokens / waves_per_block;  // 4096
    sparse_head_kernel<<<blocks, 256, 0, stream>>>(hidden, ids, mask, W, bias, out);
}

// Round 3
// 21.692 us; speedup vs baseline: 1.0712x; 1.0712x over previous
//
#include <hip/hip_runtime.h>
#include <hip/hip_bf16.h>

// Problem constants (SparseEmbeddingHead): B=32, S=512, H=1024, V=250002
#define BB 32
#define SS 512
#define HH 1024
#define VV 250002
#define TOKENS (BB * SS)          // 16384
#define OUT_FLOATS (BB * VV)      // 8000064 (divisible by 4)
#define OUT_F4 (OUT_FLOATS / 4)   // 2000016

#define K1_BLOCKS 2048
#define K1_THREADS 256

typedef float floatx4 __attribute__((ext_vector_type(4)));

// K1: fused (a) zero the [B,V] output with nontemporal float4 stores and
// (b) compute per-token weights relu((h·W + b)*mask) into ws[token].
// These two jobs are independent, so they share the HBM pipe concurrently.
// 2048 blocks x 4 waves = 8192 waves -> 2 tokens per wave.
__global__ __launch_bounds__(K1_THREADS) void k1_zero_and_dot(
    const float* __restrict__ hidden,   // [TOKENS, H]
    const float* __restrict__ mask,     // [TOKENS]
    const float* __restrict__ W,        // [H]
    const float* __restrict__ bias,     // [1]
    float* __restrict__ out,            // [B*V] — zeroed here
    float* __restrict__ tw_ws)          // [TOKENS] token weights
{
    const int tid = blockIdx.x * K1_THREADS + threadIdx.x;
    const int lane = threadIdx.x & 63;
    const int wave_global = tid >> 6;   // 0..8191

    // ---- token dot products: 2 tokens per wave ----
    const float4* __restrict__ w4 = reinterpret_cast<const float4*>(W);
    const float bias0 = bias[0];

#pragma unroll
    for (int tt = 0; tt < 2; ++tt) {
        const int token = wave_global * 2 + tt;
        const float4* __restrict__ h4 =
            reinterpret_cast<const float4*>(hidden + (size_t)token * HH);
        float sum = 0.0f;
#pragma unroll
        for (int i = 0; i < 4; ++i) {
            const float4 hv = h4[i * 64 + lane];
            const float4 wv = w4[i * 64 + lane];
            sum = fmaf(hv.x, wv.x, sum);
            sum = fmaf(hv.y, wv.y, sum);
            sum = fmaf(hv.z, wv.z, sum);
            sum = fmaf(hv.w, wv.w, sum);
        }
#pragma unroll
        for (int off = 32; off > 0; off >>= 1)
            sum += __shfl_xor(sum, off, 64);
        if (lane == 0) {
            const float tw = fmaxf((sum + bias0) * mask[token], 0.0f);
            tw_ws[token] = tw;
        }
    }

    // ---- zero the output (grid-stride float4, nontemporal) ----
    floatx4* __restrict__ o4 = reinterpret_cast<floatx4*>(out);
    const floatx4 z = {0.f, 0.f, 0.f, 0.f};
    for (int i = tid; i < OUT_F4; i += K1_BLOCKS * K1_THREADS)
        __builtin_nontemporal_store(z, &o4[i]);
}

// K2: scatter-add the 16384 token weights into out.
__global__ __launch_bounds__(256) void k2_scatter(
    const float* __restrict__ tw_ws,    // [TOKENS]
    const int* __restrict__ ids,        // [TOKENS]
    float* __restrict__ out)            // [B*V]
{
    const int t = blockIdx.x * 256 + threadIdx.x;
    if (t >= TOKENS) return;
    const float tw = tw_ws[t];
    if (tw != 0.0f) {
        const int b = t / SS;
        atomicAdd(&out[(size_t)b * VV + ids[t]], tw);
    }
}

extern "C" void kernel_launch(void* const* d_in, const int* in_sizes, int n_in,
                              void* d_out, int out_size, void* d_ws, size_t ws_size,
                              hipStream_t stream) {
    const float* hidden = (const float*)d_in[0];
    const int*   ids    = (const int*)d_in[1];
    const float* mask   = (const float*)d_in[2];
    const float* W      = (const float*)d_in[3];
    const float* bias   = (const float*)d_in[4];
    float* out   = (float*)d_out;
    float* tw_ws = (float*)d_ws;        // 16384 floats = 64 KB

    k1_zero_and_dot<<<K1_BLOCKS, K1_THREADS, 0, stream>>>(hidden, mask, W, bias, out, tw_ws);
    k2_scatter<<<(TOKENS + 255) / 256, 256, 0, stream>>>(tw_ws, ids, out);
}